// Round 1
// baseline (587.388 us; speedup 1.0000x reference)
//
#include <hip/hip_runtime.h>

#define C_CONST 3
#define B_CONST 8
#define BC 24   // B*C channels per vertex

// --- degree histogram over row indices ---
__global__ void deg_kernel(const int* __restrict__ row, int E, int* __restrict__ deg) {
    int e = blockIdx.x * blockDim.x + threadIdx.x;
    if (e < E) atomicAdd(&deg[row[e]], 1);
}

// --- dis[v] = deg>0 ? rsqrt(deg) : 0 ---
__global__ void dis_kernel(const int* __restrict__ deg, float* __restrict__ dis, int V) {
    int v = blockIdx.x * blockDim.x + threadIdx.x;
    if (v < V) {
        int d = deg[v];
        dis[v] = (d > 0) ? rsqrtf((float)d) : 0.0f;
    }
}

// --- d = x - y, transposed (B,V,C) -> (V, B*C); acc initialized with self-loop term ---
__global__ void diff_transpose_kernel(const float* __restrict__ x, const float* __restrict__ y,
                                      float* __restrict__ dtrans, float* __restrict__ acc, int V) {
    int t = blockIdx.x * blockDim.x + threadIdx.x;
    int n = V * BC;
    if (t >= n) return;
    int v = t / BC;
    int k = t - v * BC;
    int b = k / C_CONST;
    int c = k - b * C_CONST;
    int idx = (b * V + v) * C_CONST + c;
    float d = x[idx] - y[idx];
    dtrans[t] = d;
    acc[t] = d;   // self-loop weight = 1
}

// --- scatter: acc[col,k] += -dis[row]*dis[col] * dtrans[row,k] ---
__global__ void scatter_kernel(const int* __restrict__ row, const int* __restrict__ col, int E,
                               const float* __restrict__ dis, const float* __restrict__ dtrans,
                               float* __restrict__ acc) {
    int t = blockIdx.x * blockDim.x + threadIdx.x;   // E*BC = 76.8M fits in int
    int n = E * BC;
    if (t >= n) return;
    int e = t / BC;
    int k = t - e * BC;
    int r = row[e];
    int c = col[e];
    float w = -dis[r] * dis[c];
    atomicAdd(&acc[c * BC + k], w * dtrans[r * BC + k]);
}

// --- sum of squares -> mean ---
__global__ void reduce_kernel(const float* __restrict__ acc, int n, float inv_n,
                              float* __restrict__ out) {
    float s = 0.0f;
    for (int i = blockIdx.x * blockDim.x + threadIdx.x; i < n; i += gridDim.x * blockDim.x) {
        float v = acc[i];
        s += v * v;
    }
    // wave-64 butterfly
    for (int off = 32; off > 0; off >>= 1) s += __shfl_down(s, off, 64);
    __shared__ float ls[4];
    int lane = threadIdx.x & 63;
    int wid  = threadIdx.x >> 6;
    if (lane == 0) ls[wid] = s;
    __syncthreads();
    if (threadIdx.x == 0) {
        float tot = 0.0f;
        int nw = blockDim.x >> 6;
        for (int i = 0; i < nw; i++) tot += ls[i];
        atomicAdd(out, tot * inv_n);
    }
}

extern "C" void kernel_launch(void* const* d_in, const int* in_sizes, int n_in,
                              void* d_out, int out_size, void* d_ws, size_t ws_size,
                              hipStream_t stream) {
    const float* x = (const float*)d_in[0];         // (B,V,C)
    const float* y = (const float*)d_in[1];         // (B,V,C)
    const int*  ei = (const int*)d_in[2];           // (2,E)

    const int E = in_sizes[2] / 2;
    const int V = in_sizes[0] / (B_CONST * C_CONST);
    const int* row = ei;
    const int* col = ei + E;

    char* ws = (char*)d_ws;
    int*   deg    = (int*)ws;                                   // V ints
    float* dis    = (float*)(ws + (size_t)V * 4);               // V floats
    float* dtrans = (float*)(ws + (size_t)V * 8);               // V*24 floats
    float* acc    = dtrans + (size_t)V * BC;                    // V*24 floats
    float* outf   = (float*)d_out;

    hipMemsetAsync(deg, 0, (size_t)V * sizeof(int), stream);
    hipMemsetAsync(d_out, 0, sizeof(float), stream);

    deg_kernel<<<(E + 255) / 256, 256, 0, stream>>>(row, E, deg);
    dis_kernel<<<(V + 255) / 256, 256, 0, stream>>>(deg, dis, V);
    diff_transpose_kernel<<<(V * BC + 255) / 256, 256, 0, stream>>>(x, y, dtrans, acc, V);
    scatter_kernel<<<(E * BC + 255) / 256, 256, 0, stream>>>(row, col, E, dis, dtrans, acc);
    reduce_kernel<<<2048, 256, 0, stream>>>(acc, V * BC, 1.0f / (float)(V * BC), outf);
}